// Round 9
// baseline (546.117 us; speedup 1.0000x reference)
//
#include <hip/hip_runtime.h>
#include <math.h>
#include <cstddef>
#include <cstdint>

// ---------------------------------------------------------------------------
// B=16, N=1024, C=768, H=12, d=64.  All stages on MFMA via f16 hi/lo split
// (3 mfma per product: hi*hi + lo*hi + hi*lo ~ fp32 accuracy, fp32 accum).
//   conv:  x -> xhi/xlo planes; w_qkv,w_proj -> transposed hi/lo planes
//   gemm1: qkv = x @ w_qkv          (split-f16 MFMA, 2-phase dbuf BK=32)
//   prep:  K,V slots of qkv -> f16 hi/lo in place (V transposed, k-permuted)
//   attn:  flash attention (split-f16 MFMA), no-max softmax, counted-vmcnt
//          K/V pipeline, packed-b64 P (k-permuted + slot-XOR swizzled),
//          XCD-grouped blocks (K/V L2-resident per (b,h)).
//   gemm2: out = attn @ w_proj + b  (split-f16 MFMA, 2-phase dbuf BK=32)
// ---------------------------------------------------------------------------

typedef _Float16 half8 __attribute__((ext_vector_type(8)));
typedef _Float16 half4 __attribute__((ext_vector_type(4)));
typedef float f32x4 __attribute__((ext_vector_type(4)));

__device__ __forceinline__ void async_ld16(const void* src, void* lds) {
  __builtin_amdgcn_global_load_lds(
      (const __attribute__((address_space(1))) unsigned int*)src,
      (__attribute__((address_space(3))) unsigned int*)lds, 16, 0, 0);
}

__device__ __forceinline__ f32x4 mfma16(half8 a, half8 b, f32x4 c) {
  return __builtin_amdgcn_mfma_f32_16x16x32_f16(a, b, c, 0, 0, 0);
}

// ===================== conv: f32 -> f16 hi/lo planes (no transpose) ========
__global__ __launch_bounds__(256) void conv_split(const float* __restrict__ src,
                                                  _Float16* __restrict__ hi,
                                                  _Float16* __restrict__ lo,
                                                  int n8) {
  for (int i = blockIdx.x * blockDim.x + threadIdx.x; i < n8;
       i += gridDim.x * blockDim.x) {
    const float4 f0 = ((const float4*)src)[i * 2];
    const float4 f1 = ((const float4*)src)[i * 2 + 1];
    const float x[8] = {f0.x, f0.y, f0.z, f0.w, f1.x, f1.y, f1.z, f1.w};
    half8 h, l;
#pragma unroll
    for (int j = 0; j < 8; ++j) {
      const _Float16 hv = (_Float16)x[j];
      h[j] = hv;
      l[j] = (_Float16)(x[j] - (float)hv);
    }
    ((half8*)hi)[i] = h;
    ((half8*)lo)[i] = l;
  }
}

// ========== conv: W[K][N] f32 -> Wt_hi/Wt_lo [N][K] f16 (transpose) ========
__global__ __launch_bounds__(256) void conv_wT(const float* __restrict__ W,
                                               _Float16* __restrict__ Th,
                                               _Float16* __restrict__ Tl,
                                               int K, int N) {
  __shared__ float T[64][65];
  const int n0 = blockIdx.x * 64, k0 = blockIdx.y * 64;
  const int t = threadIdx.x, r = t >> 2, c4 = t & 3;
#pragma unroll
  for (int q = 0; q < 4; ++q) {
    const float4 v = *reinterpret_cast<const float4*>(
        &W[(size_t)(k0 + r) * N + n0 + c4 * 16 + q * 4]);
    T[r][c4 * 16 + q * 4 + 0] = v.x;
    T[r][c4 * 16 + q * 4 + 1] = v.y;
    T[r][c4 * 16 + q * 4 + 2] = v.z;
    T[r][c4 * 16 + q * 4 + 3] = v.w;
  }
  __syncthreads();
  half8 h0, h1, l0, l1;
#pragma unroll
  for (int j = 0; j < 8; ++j) {
    const float x0 = T[c4 * 16 + j][r];
    const _Float16 hv0 = (_Float16)x0;
    h0[j] = hv0; l0[j] = (_Float16)(x0 - (float)hv0);
    const float x1 = T[c4 * 16 + 8 + j][r];
    const _Float16 hv1 = (_Float16)x1;
    h1[j] = hv1; l1[j] = (_Float16)(x1 - (float)hv1);
  }
  const size_t ob = (size_t)(n0 + r) * K + k0 + c4 * 16;
  *(half8*)&Th[ob] = h0;
  *(half8*)&Th[ob + 8] = h1;
  *(half8*)&Tl[ob] = l0;
  *(half8*)&Tl[ob + 8] = l1;
}

// ===================== split-f16 MFMA GEMM, 2-phase dbuf ===================
// C[M,N] = A @ B; A hi/lo [M][K], B hi/lo [N][K] (B^T). 128x128 tile, BK=32,
// double-buffered LDS (64 KB), 4 waves 2x2. Stage(t+1) issued BEFORE
// compute(t); the single __syncthreads per K-step drains vmcnt AFTER the
// compute block has covered the load latency (T3 minimum-2-phase).
// Slot swizzle: 4x16B slots/row, phys slot = logical ^ ((row>>1)&3); source
// pre-swizzled, LDS dest linear, read applies the same XOR -> 2-way max.
template <bool HAS_BIAS>
__global__ __launch_bounds__(256, 2) void gemm_split(
    const _Float16* __restrict__ Ah, const _Float16* __restrict__ Al,
    const _Float16* __restrict__ Bh, const _Float16* __restrict__ Bl,
    const float* __restrict__ bias, float* __restrict__ C,
    int M, int N, int K) {
  __shared__ _Float16 AsH[2][128 * 32], AsL[2][128 * 32];
  __shared__ _Float16 BsH[2][128 * 32], BsL[2][128 * 32];
  const int tid = threadIdx.x;
  const int w = tid >> 6, l = tid & 63;
  const int kl = l & 15, lgrp = l >> 4;
  const int rl4 = l >> 2, cl4 = l & 3;  // staging: row-in-16 / 16B-slot
  const int bm = blockIdx.y * 128, bn = blockIdx.x * 128;
  const int wm = (w & 1) * 64, wn = (w >> 1) * 64;

  f32x4 acc[4][4];
#pragma unroll
  for (int m = 0; m < 4; ++m)
#pragma unroll
    for (int n = 0; n < 4; ++n) acc[m][n] = f32x4{0.f, 0.f, 0.f, 0.f};

  const int nt = K >> 5;

  auto stage = [&](int t, int buf) {
    const int k0 = t << 5;
#pragma unroll
    for (int j = 0; j < 2; ++j) {
      const int row = w * 32 + j * 16 + rl4;
      const size_t koff = (size_t)k0 + ((cl4 ^ ((row >> 1) & 3)) << 3);
      const int ldsb = (w * 32 + j * 16) * 32;  // wave-uniform dest base
      async_ld16(Ah + (size_t)(bm + row) * K + koff, &AsH[buf][ldsb]);
      async_ld16(Al + (size_t)(bm + row) * K + koff, &AsL[buf][ldsb]);
      async_ld16(Bh + (size_t)(bn + row) * K + koff, &BsH[buf][ldsb]);
      async_ld16(Bl + (size_t)(bn + row) * K + koff, &BsL[buf][ldsb]);
    }
  };

  stage(0, 0);
  __syncthreads();

  int cur = 0;
  for (int t = 0; t < nt; ++t) {
    if (t + 1 < nt) stage(t + 1, cur ^ 1);  // overlaps with compute below

    half8 ah[4], al[4], bh[4], bl[4];
#pragma unroll
    for (int m = 0; m < 4; ++m) {
      const int row = wm + m * 16 + kl;
      const int off = row * 32 + ((lgrp ^ ((row >> 1) & 3)) << 3);
      ah[m] = *(const half8*)&AsH[cur][off];
      al[m] = *(const half8*)&AsL[cur][off];
    }
#pragma unroll
    for (int n = 0; n < 4; ++n) {
      const int row = wn + n * 16 + kl;
      const int off = row * 32 + ((lgrp ^ ((row >> 1) & 3)) << 3);
      bh[n] = *(const half8*)&BsH[cur][off];
      bl[n] = *(const half8*)&BsL[cur][off];
    }
#pragma unroll
    for (int m = 0; m < 4; ++m)
#pragma unroll
      for (int n = 0; n < 4; ++n) {
        acc[m][n] = mfma16(ah[m], bh[n], acc[m][n]);
        acc[m][n] = mfma16(al[m], bh[n], acc[m][n]);
        acc[m][n] = mfma16(ah[m], bl[n], acc[m][n]);
      }

    __syncthreads();  // drains vmcnt (next buffer landed) + lgkm; one/K-step
    cur ^= 1;
  }

  float bv[4];
  if (HAS_BIAS) {
#pragma unroll
    for (int n = 0; n < 4; ++n) bv[n] = bias[bn + wn + n * 16 + kl];
  }
#pragma unroll
  for (int m = 0; m < 4; ++m)
#pragma unroll
    for (int r = 0; r < 4; ++r) {
      const int row = bm + wm + m * 16 + lgrp * 4 + r;
#pragma unroll
      for (int n = 0; n < 4; ++n) {
        float v = acc[m][n][r];
        if (HAS_BIAS) v += bv[n];
        C[(size_t)row * N + bn + wn + n * 16 + kl] = v;
      }
    }
}

// ===================== prep: K,V -> f16 hi/lo in place =====================
// V^T slot: position p (of 64 halves) holds V[kappa(p)][dd],
// kappa(p) = (p&3)*16 + (p>>2) — matches attn's packed-P k-order.
__global__ __launch_bounds__(256) void prep_kv(float* __restrict__ qkv) {
  constexpr int N = 1024, C3 = 2304;
  const int nt = blockIdx.x, h = blockIdx.y, b = blockIdx.z;
  const int t = threadIdx.x;
  __shared__ float Vls[64 * 65];

  const int r = t >> 2, dc = t & 3;
  const size_t rowf = (size_t)(b * N + nt * 64 + r) * C3 + h * 64;

  float kx[16], vx[16];
#pragma unroll
  for (int q = 0; q < 4; ++q) {
    const float4 kv = *reinterpret_cast<const float4*>(&qkv[rowf + 768 + dc * 16 + q * 4]);
    kx[q * 4 + 0] = kv.x; kx[q * 4 + 1] = kv.y; kx[q * 4 + 2] = kv.z; kx[q * 4 + 3] = kv.w;
    const float4 vv = *reinterpret_cast<const float4*>(&qkv[rowf + 1536 + dc * 16 + q * 4]);
    vx[q * 4 + 0] = vv.x; vx[q * 4 + 1] = vv.y; vx[q * 4 + 2] = vv.z; vx[q * 4 + 3] = vv.w;
  }
#pragma unroll
  for (int i = 0; i < 16; ++i) Vls[r * 65 + dc * 16 + i] = vx[i];
  __syncthreads();

  {
    char* base = (char*)qkv + (rowf + 768) * 4;
    half8 h0, h1, l0, l1;
#pragma unroll
    for (int i = 0; i < 8; ++i) {
      const _Float16 hi = (_Float16)kx[i];
      h0[i] = hi; l0[i] = (_Float16)(kx[i] - (float)hi);
      const _Float16 hi2 = (_Float16)kx[i + 8];
      h1[i] = hi2; l1[i] = (_Float16)(kx[i + 8] - (float)hi2);
    }
    *(half8*)(base + dc * 32) = h0;
    *(half8*)(base + dc * 32 + 16) = h1;
    *(half8*)(base + 128 + dc * 32) = l0;
    *(half8*)(base + 128 + dc * 32 + 16) = l1;
  }

#pragma unroll
  for (int p = 0; p < 2; ++p) {
    const int dd = p * 32 + (t >> 3), nc = t & 7;
    half8 hv, lv;
#pragma unroll
    for (int j = 0; j < 8; ++j) {
      const int pos = nc * 8 + j;                       // half-position in slot
      const int kap = ((pos & 3) << 4) | (pos >> 2);    // source k row
      const float x = Vls[kap * 65 + dd];
      const _Float16 hi = (_Float16)x;
      hv[j] = hi; lv[j] = (_Float16)(x - (float)hi);
    }
    char* vb = (char*)qkv + ((size_t)(b * N + nt * 64 + dd) * C3 + h * 64 + 1536) * 4;
    *(half8*)(vb + nc * 16) = hv;
    *(half8*)(vb + 128 + nc * 16) = lv;
  }
}

// ===================== flash attention, f16-split MFMA =====================
// No-max softmax + counted-vmcnt K/V pipeline + packed-b64 P (k-permuted,
// slot-XOR swizzled: phys half = logical ^ ((prow&7)<<3), involution on both
// write and read -> 2-way max) + XCD-grouped block swizzle.
__global__ __launch_bounds__(256, 2) void attn_mfma(const float* __restrict__ qkv,
                                                    _Float16* __restrict__ ahi,
                                                    _Float16* __restrict__ alo) {
  constexpr int N = 1024, H = 12, C3 = 2304;
  // Grid: 1536 = 8 xcd * 24 bh-groups * 8 qt.  (b,h) pinned to one XCD.
  const int blk = blockIdx.x;
  const int xcd = blk & 7;
  const int slot = blk >> 3;       // 0..191
  const int qt = slot & 7;
  const int bh = xcd * 24 + (slot >> 3);
  const int h = bh % H;
  const int b = bh / H;

  const int tid = threadIdx.x;
  const int w = tid >> 6, l = tid & 63;
  const int kl = l & 15, lgrp = l >> 4;

  __shared__ _Float16 Khi[64 * 64], Klo[64 * 64], Vhi[64 * 64], Vlo[64 * 64];
  __shared__ _Float16 Phi[128 * 64], Plo[128 * 64];  // packed+swizzled

  const int q0 = qt * 128;

  half8 qhi[2][2], qlo[2][2];
#pragma unroll
  for (int qs = 0; qs < 2; ++qs)
#pragma unroll
    for (int ks = 0; ks < 2; ++ks) {
      const float* qp = qkv + (size_t)(b * N + q0 + w * 32 + qs * 16 + kl) * C3 +
                        h * 64 + ks * 32 + lgrp * 8;
      const float4 f0 = *reinterpret_cast<const float4*>(qp);
      const float4 f1 = *reinterpret_cast<const float4*>(qp + 4);
      const float x[8] = {f0.x, f0.y, f0.z, f0.w, f1.x, f1.y, f1.z, f1.w};
#pragma unroll
      for (int j = 0; j < 8; ++j) {
        const float xs = x[j] * 0.125f;
        const _Float16 hi = (_Float16)xs;
        qhi[qs][ks][j] = hi;
        qlo[qs][ks][j] = (_Float16)(xs - (float)hi);
      }
    }

  f32x4 o[2][4];
  float plsum[2][4];  // per-lane partial row-sum of exp(S); reduced at end
#pragma unroll
  for (int qs = 0; qs < 2; ++qs)
#pragma unroll
    for (int i = 0; i < 4; ++i) {
      plsum[qs][i] = 0.f;
      o[qs][i] = f32x4{0.f, 0.f, 0.f, 0.f};
    }

  const char* qkvB = (const char*)qkv;
  const int rl = l >> 3, cl = l & 7;

  auto stageK = [&](int kb) {
#pragma unroll
    for (int i = 0; i < 2; ++i) {
      const int row = w * 16 + i * 8 + rl;
      const size_t rb = ((size_t)(b * N + kb * 64 + row) * C3 + h * 64) * 4;
      const int sw = (cl ^ (row & 7)) * 16;
      const char* kc = qkvB + rb + 768 * 4 + sw;
      const int lo_ = (w * 16 + i * 8) * 64;
      async_ld16(kc, &Khi[lo_]);
      async_ld16(kc + 128, &Klo[lo_]);
    }
  };
  auto stageV = [&](int kb) {
#pragma unroll
    for (int i = 0; i < 2; ++i) {
      const int row = w * 16 + i * 8 + rl;
      const size_t rb = ((size_t)(b * N + kb * 64 + row) * C3 + h * 64) * 4;
      const int sw = (cl ^ (row & 7)) * 16;
      const char* vc = qkvB + rb + 1536 * 4 + sw;
      const int lo_ = (w * 16 + i * 8) * 64;
      async_ld16(vc, &Vhi[lo_]);
      async_ld16(vc + 128, &Vlo[lo_]);
    }
  };

  stageK(0);
  stageV(0);
  asm volatile("s_waitcnt vmcnt(0)" ::: "memory");
  __builtin_amdgcn_s_barrier();

  for (int kb = 0; kb < 16; ++kb) {
    // ---- S = (Q/8) K^T ----
    f32x4 s[2][4];
#pragma unroll
    for (int qs = 0; qs < 2; ++qs)
#pragma unroll
      for (int kt = 0; kt < 4; ++kt) s[qs][kt] = f32x4{0.f, 0.f, 0.f, 0.f};

#pragma unroll
    for (int kt = 0; kt < 4; ++kt)
#pragma unroll
      for (int ks = 0; ks < 2; ++ks) {
        const int rowb = kt * 16 + kl;
        const int off = rowb * 64 + (((ks * 4 + lgrp) ^ (rowb & 7)) << 3);
        const half8 bh_ = *(const half8*)&Khi[off];
        const half8 bl_ = *(const half8*)&Klo[off];
#pragma unroll
        for (int qs = 0; qs < 2; ++qs) {
          s[qs][kt] = mfma16(qhi[qs][ks], bh_, s[qs][kt]);
          s[qs][kt] = mfma16(qlo[qs][ks], bh_, s[qs][kt]);
          s[qs][kt] = mfma16(qhi[qs][ks], bl_, s[qs][kt]);
        }
      }

    // V(kb) landed; all waves done reading K(kb).
    asm volatile("s_waitcnt vmcnt(0)" ::: "memory");
    __builtin_amdgcn_s_barrier();
    if (kb < 15) stageK(kb + 1);  // flies under softmax + PV

    // ---- softmax (no max-sub); packed-b64 P hi/lo, slot-XOR swizzled ----
    // Logical half-position p = kl*4 + kt holds score col kappa(p); phys
    // half = logical ^ ((prow&7)<<3)  (XOR touches bits 3-5 only: the half4
    // at kl*4 stays contiguous since kl*4 mod 8 in {0,4}).
#pragma unroll
    for (int qs = 0; qs < 2; ++qs)
#pragma unroll
      for (int r = 0; r < 4; ++r) {
        const int prow = w * 32 + qs * 16 + lgrp * 4 + r;
        const int swz = (prow & 7) << 3;
        float ps = 0.f;
        half4 ph4, pl4;
#pragma unroll
        for (int kt = 0; kt < 4; ++kt) {
          const float p = __expf(s[qs][kt][r]);
          ps += p;
          const _Float16 ph = (_Float16)p;
          ph4[kt] = ph;
          pl4[kt] = (_Float16)(p - (float)ph);
        }
        *(half4*)&Phi[prow * 64 + ((kl * 4) ^ swz)] = ph4;
        *(half4*)&Plo[prow * 64 + ((kl * 4) ^ swz)] = pl4;
        plsum[qs][r] += ps;
      }

    // ---- O += P V (wave-local P rows; swizzled b128 reads, 2-way max) ----
#pragma unroll
    for (int ks = 0; ks < 2; ++ks) {
      half8 pah[2], pal[2];
#pragma unroll
      for (int qs = 0; qs < 2; ++qs) {
        const int prow = w * 32 + qs * 16 + kl;
        const int off = prow * 64 + ((ks * 32 + lgrp * 8) ^ ((prow & 7) << 3));
        pah[qs] = *(const half8*)&Phi[off];
        pal[qs] = *(const half8*)&Plo[off];
      }
#pragma unroll
      for (int dt = 0; dt < 4; ++dt) {
        const int rowv = dt * 16 + kl;
        const int off = rowv * 64 + (((ks * 4 + lgrp) ^ (rowv & 7)) << 3);
        const half8 vh = *(const half8*)&Vhi[off];
        const half8 vl = *(const half8*)&Vlo[off];
#pragma unroll
        for (int qs = 0; qs < 2; ++qs) {
          o[qs][dt] = mfma16(pah[qs], vh, o[qs][dt]);
          o[qs][dt] = mfma16(pah[qs], vl, o[qs][dt]);
          o[qs][dt] = mfma16(pal[qs], vh, o[qs][dt]);
        }
      }
    }

    // All waves done reading V(kb).
    __builtin_amdgcn_s_barrier();
    if (kb < 15) {
      stageV(kb + 1);
      asm volatile("s_waitcnt vmcnt(4)" ::: "memory");  // K(kb+1) landed
    } else {
      asm volatile("s_waitcnt vmcnt(0)" ::: "memory");
    }
    __builtin_amdgcn_s_barrier();
  }

  // ---- epilogue: reduce l across the 16-lane row group, normalize ----
#pragma unroll
  for (int qs = 0; qs < 2; ++qs)
#pragma unroll
    for (int r = 0; r < 4; ++r) {
      float lsum = plsum[qs][r];
#pragma unroll
      for (int ofs = 1; ofs < 16; ofs <<= 1) lsum += __shfl_xor(lsum, ofs);
      const float inv = 1.f / lsum;
      const int qg = q0 + w * 32 + qs * 16 + lgrp * 4 + r;
      const size_t ob = ((size_t)(b * H + h) * N + qg) * 64;
#pragma unroll
      for (int dt = 0; dt < 4; ++dt) {
        const float v = o[qs][dt][r] * inv;
        const _Float16 hv = (_Float16)v;
        ahi[ob + dt * 16 + kl] = hv;
        alo[ob + dt * 16 + kl] = (_Float16)(v - (float)hv);
      }
    }
}

// ===========================================================================
extern "C" void kernel_launch(void* const* d_in, const int* in_sizes, int n_in,
                              void* d_out, int out_size, void* d_ws,
                              size_t ws_size, hipStream_t stream) {
  const float* x = (const float*)d_in[0];       // [16,1024,768]
  const float* w_qkv = (const float*)d_in[1];   // [768,2304]
  const float* w_proj = (const float*)d_in[2];  // [768,768]
  const float* b_proj = (const float*)d_in[3];  // [768]
  float* out = (float*)d_out;                   // [16,1024,768]

  constexpr int M = 16 * 1024;
  constexpr int C = 768;
  constexpr int C3 = 2304;

  char* wsp = (char*)d_ws;
  float* qkv = (float*)wsp;
  _Float16* xhi = (_Float16*)(wsp + (size_t)M * C3 * 4);
  _Float16* xlo = xhi + (size_t)M * C;
  _Float16* wqh = xlo + (size_t)M * C;
  _Float16* wql = wqh + (size_t)C3 * C;
  _Float16* wph = wql + (size_t)C3 * C;
  _Float16* wpl = wph + (size_t)C * C;
  _Float16* ahi = xhi;  // x planes dead after gemm1
  _Float16* alo = xlo;

  conv_split<<<2048, 256, 0, stream>>>(x, xhi, xlo, M * C / 8);
  conv_wT<<<dim3(C3 / 64, C / 64), 256, 0, stream>>>(w_qkv, wqh, wql, C, C3);
  conv_wT<<<dim3(C / 64, C / 64), 256, 0, stream>>>(w_proj, wph, wpl, C, C);

  gemm_split<false><<<dim3(C3 / 128, M / 128), 256, 0, stream>>>(
      xhi, xlo, wqh, wql, nullptr, qkv, M, C3, C);

  prep_kv<<<dim3(16, 12, 16), 256, 0, stream>>>(qkv);

  attn_mfma<<<1536, 256, 0, stream>>>(qkv, ahi, alo);

  gemm_split<true><<<dim3(C / 128, M / 128), 256, 0, stream>>>(
      ahi, alo, wph, wpl, b_proj, out, M, C, C);
}